// Round 6
// baseline (141.019 us; speedup 1.0000x reference)
//
#include <hip/hip_runtime.h>

#define WID 256
#define HEI 256
#define CH  64
#define GRP 8
#define CPG 8
#define ND  9
#define HW  (HEI * WID)
#define ROWP 264               // 256 row + 8 shared zero pad
#define WVF (8 + CPG * ROWP)   // 2120 floats per wave region

typedef float vf4 __attribute__((ext_vector_type(4)));

__global__ __launch_bounds__(256, 4)
void cost_volume_kernel(const float* __restrict__ L,
                        const float* __restrict__ R,
                        const float* __restrict__ disp,
                        float* __restrict__ out) {
    // per-wave private region: [8 zero][row0 256][8 zero][row1 256]...[8 zero]
    __shared__ __align__(16) float sR[4][WVF];

    const int bid  = blockIdx.x;          // b*512 + h*2 + gq
    const int gq   = bid & 1;
    const int h    = (bid >> 1) & 255;
    const int b    = bid >> 9;
    const int tid  = threadIdx.x;
    const int wv   = tid >> 6;
    const int lane = tid & 63;
    const int g    = gq * 4 + wv;         // this wave's group
    const int wb   = lane * 4;            // first of 4 w positions

    // ---- stage this group's 8 channel-rows (wave-local, no halo) ----
    #pragma unroll
    for (int c = 0; c < CPG; ++c) {
        const float* gsrc = R + ((size_t)(b * CH + g * CPG + c) * HEI + h) * WID + wb;
        __builtin_amdgcn_global_load_lds(
            (const __attribute__((address_space(1))) void*)gsrc,
            (__attribute__((address_space(3))) void*)&sR[wv][8 + ROWP * c],
            16, 0, 0);
    }
    // zero the 9 pad regions (8 floats each, 72 total) — wave-local
    {
        const int off = ROWP * (lane >> 3) + (lane & 7);
        sR[wv][off] = 0.0f;
        if (lane < 8) sR[wv][ROWP * 8 + lane] = 0.0f;
    }

    // ---- independent VMEM/VALU while staging is in flight ----
    const vf4 dv4 = *reinterpret_cast<const vf4*>(
        disp + (size_t)b * HW + (size_t)h * WID + wb);

    vf4 l4[CPG];
    #pragma unroll
    for (int c = 0; c < CPG; ++c)
        l4[c] = *reinterpret_cast<const vf4*>(
            L + ((size_t)(b * CH + g * CPG + c) * HEI + h) * WID + wb);

    // per-q 3-tap weights: out_d = a*U[8-d] + b*U[9-d] + c*U[10-d]
    float wa[4], wb_[4], wc[4];
    #pragma unroll
    for (int q = 0; q < 4; ++q) {
        const float dv   = dv4[q];
        const float wq   = (float)(wb + q);
        const float base = wq - dv;
        const float fb   = floorf(base);
        const float f    = base - fb;
        const float A  = (1.0f - f) * 0.125f;
        const float Bv = f * 0.125f;
        const bool dlt = (fb > wq - 0.5f);   // fib == w  (dv == 0)
        wa[q]  = dlt ? 0.0f : A;
        wb_[q] = dlt ? A    : Bv;
        wc[q]  = dlt ? Bv   : 0.0f;
    }

    asm volatile("s_waitcnt vmcnt(0) lgkmcnt(0)" ::: "memory");

    // ---- U[q][i] = sum_c l_c[w_q] * rpad_c[w_q - 5 + i], i = 0..10 ----
    float U[4][11];
    #pragma unroll
    for (int q = 0; q < 4; ++q)
        #pragma unroll
        for (int i = 0; i < 11; ++i) U[q][i] = 0.0f;

    #pragma unroll
    for (int c = 0; c < CPG; ++c) {
        // aligned 20-float window covering x = [wb-8, wb+12)
        const vf4* p = reinterpret_cast<const vf4*>(
            &sR[wv][ROWP * c + wb]);         // = base of x = wb-8 (8-float pad offset)
        const vf4 w0 = p[0], w1 = p[1], w2 = p[2], w3 = p[3], w4 = p[4];
        float W[20];
        #pragma unroll
        for (int u = 0; u < 4; ++u) {
            W[u]      = w0[u];
            W[u + 4]  = w1[u];
            W[u + 8]  = w2[u];
            W[u + 12] = w3[u];
            W[u + 16] = w4[u];
        }
        #pragma unroll
        for (int q = 0; q < 4; ++q) {
            const float lv = l4[c][q];
            #pragma unroll
            for (int i = 0; i < 11; ++i)
                U[q][i] = fmaf(lv, W[q + i + 3], U[q][i]);
        }
    }

    // ---- combine per offset d and store 4 w at once (plain dwordx4) ----
    const size_t ob = ((size_t)(b * GRP + g) * ND) * HW + (size_t)h * WID + wb;
    #pragma unroll
    for (int d = 0; d < ND; ++d) {
        vf4 o;
        #pragma unroll
        for (int q = 0; q < 4; ++q)
            o[q] = fmaf(wa[q], U[q][8 - d],
                   fmaf(wb_[q], U[q][9 - d], wc[q] * U[q][10 - d]));
        *reinterpret_cast<vf4*>(out + ob + (size_t)d * HW) = o;
    }
}

extern "C" void kernel_launch(void* const* d_in, const int* in_sizes, int n_in,
                              void* d_out, int out_size, void* d_ws, size_t ws_size,
                              hipStream_t stream) {
    const float* feat_left  = (const float*)d_in[0];
    const float* feat_right = (const float*)d_in[1];
    const float* disp_init  = (const float*)d_in[2];
    float* out = (float*)d_out;

    dim3 grid(8 * HEI * 2);   // (b, h, group-quad)
    dim3 block(256);          // 4 waves, one group each
    cost_volume_kernel<<<grid, block, 0, stream>>>(feat_left, feat_right, disp_init, out);
}

// Round 7
// 86.747 us; speedup vs baseline: 1.6256x; 1.6256x over previous
//
#include <hip/hip_runtime.h>

#define WID 256
#define HEI 256
#define CH  64
#define GRP 8
#define CPG 8
#define ND  9
#define HW  (HEI * WID)
#define ROWP 264               // 256 row + 8 shared zero pad
#define WVF (8 + CPG * ROWP)   // 2120 floats per wave region

typedef float vf4 __attribute__((ext_vector_type(4)));

__global__
__attribute__((amdgpu_flat_work_group_size(256, 256), amdgpu_waves_per_eu(4, 4)))
void cost_volume_kernel(const float* __restrict__ L,
                        const float* __restrict__ R,
                        const float* __restrict__ disp,
                        float* __restrict__ out) {
    // per-wave private region: [8 zero][row0 256][8 zero][row1 256]...[8 zero]
    __shared__ __align__(16) float sR[4][WVF];

    const int bid  = blockIdx.x;          // b*512 + h*2 + gq
    const int gq   = bid & 1;
    const int h    = (bid >> 1) & 255;
    const int b    = bid >> 9;
    const int tid  = threadIdx.x;
    const int wv   = tid >> 6;
    const int lane = tid & 63;
    const int g    = gq * 4 + wv;         // this wave's group
    const int wb   = lane * 4;            // first of 4 w positions

    // ---- stage this group's 8 channel-rows (wave-local, no halo) ----
    #pragma unroll
    for (int c = 0; c < CPG; ++c) {
        const float* gsrc = R + ((size_t)(b * CH + g * CPG + c) * HEI + h) * WID + wb;
        __builtin_amdgcn_global_load_lds(
            (const __attribute__((address_space(1))) void*)gsrc,
            (__attribute__((address_space(3))) void*)&sR[wv][8 + ROWP * c],
            16, 0, 0);
    }
    // zero the 9 pad regions (8 floats each) — wave-local
    {
        const int off = ROWP * (lane >> 3) + (lane & 7);
        sR[wv][off] = 0.0f;
        if (lane < 8) sR[wv][ROWP * 8 + lane] = 0.0f;
    }

    // ---- independent VMEM/VALU while staging is in flight ----
    const vf4 dv4 = *reinterpret_cast<const vf4*>(
        disp + (size_t)b * HW + (size_t)h * WID + wb);

    const float* Lg = L + ((size_t)(b * CH + g * CPG) * HEI + h) * WID + wb;

    // per-q 3-tap weights: out_d = a*U[8-d] + b*U[9-d] + c*U[10-d]
    float wa[4], wb_[4], wc[4];
    #pragma unroll
    for (int q = 0; q < 4; ++q) {
        const float dv   = dv4[q];
        const float wq   = (float)(wb + q);
        const float base = wq - dv;
        const float fb   = floorf(base);
        const float f    = base - fb;
        const float A  = (1.0f - f) * 0.125f;
        const float Bv = f * 0.125f;
        const bool dlt = (fb > wq - 0.5f);   // fib == w  (dv == 0)
        wa[q]  = dlt ? 0.0f : A;
        wb_[q] = dlt ? A    : Bv;
        wc[q]  = dlt ? Bv   : 0.0f;
    }

    // prefetch left channel c=0
    vf4 lcur = *reinterpret_cast<const vf4*>(Lg);

    // drain staging (and the issued loads) before reading own LDS quarter
    asm volatile("s_waitcnt vmcnt(0) lgkmcnt(0)" ::: "memory");

    // ---- U[q][i] = sum_c l_c[w_q] * rpad_c[w_q - 5 + i], i = 0..10 ----
    float U[4][11];
    #pragma unroll
    for (int q = 0; q < 4; ++q)
        #pragma unroll
        for (int i = 0; i < 11; ++i) U[q][i] = 0.0f;

    #pragma unroll 1
    for (int c = 0; c < CPG; ++c) {
        // software-pipelined left load for next channel (depth 1)
        vf4 lnext = lcur;
        if (c + 1 < CPG)
            lnext = *reinterpret_cast<const vf4*>(Lg + (size_t)(c + 1) * HW);

        // aligned 20-float window covering x = [wb-8, wb+12)
        const vf4* p = reinterpret_cast<const vf4*>(&sR[wv][ROWP * c + wb]);
        const vf4 w0 = p[0], w1 = p[1], w2 = p[2], w3 = p[3], w4 = p[4];
        float W[20];
        #pragma unroll
        for (int u = 0; u < 4; ++u) {
            W[u]      = w0[u];
            W[u + 4]  = w1[u];
            W[u + 8]  = w2[u];
            W[u + 12] = w3[u];
            W[u + 16] = w4[u];
        }
        #pragma unroll
        for (int q = 0; q < 4; ++q) {
            const float lv = lcur[q];
            #pragma unroll
            for (int i = 0; i < 11; ++i)
                U[q][i] = fmaf(lv, W[q + i + 3], U[q][i]);
        }
        lcur = lnext;
    }

    // ---- combine per offset d and store 4 w at once (plain dwordx4) ----
    const size_t ob = ((size_t)(b * GRP + g) * ND) * HW + (size_t)h * WID + wb;
    #pragma unroll
    for (int d = 0; d < ND; ++d) {
        vf4 o;
        #pragma unroll
        for (int q = 0; q < 4; ++q)
            o[q] = fmaf(wa[q], U[q][8 - d],
                   fmaf(wb_[q], U[q][9 - d], wc[q] * U[q][10 - d]));
        *reinterpret_cast<vf4*>(out + ob + (size_t)d * HW) = o;
    }
}

extern "C" void kernel_launch(void* const* d_in, const int* in_sizes, int n_in,
                              void* d_out, int out_size, void* d_ws, size_t ws_size,
                              hipStream_t stream) {
    const float* feat_left  = (const float*)d_in[0];
    const float* feat_right = (const float*)d_in[1];
    const float* disp_init  = (const float*)d_in[2];
    float* out = (float*)d_out;

    dim3 grid(8 * HEI * 2);   // (b, h, group-quad)
    dim3 block(256);          // 4 waves, one group each
    cost_volume_kernel<<<grid, block, 0, stream>>>(feat_left, feat_right, disp_init, out);
}